// Round 7
// baseline (214.042 us; speedup 1.0000x reference)
//
#include <hip/hip_runtime.h>
#include <stdint.h>

#define BATCH 8
#define NN 4096
#define CC 64
#define MASKV -1.0e30f
#define LOG2E 1.4426950408889634f

typedef _Float16 half8 __attribute__((ext_vector_type(8)));
typedef __fp16 fp16x2 __attribute__((ext_vector_type(2)));
typedef float f32x4 __attribute__((ext_vector_type(4)));

// ------------------------------------------------------------------
// Fused prep: blocks [0,512) do the projections (q fp16 hi/lo scaled
// by log2e, k fp16, vT fp16 [b][c][n]); blocks [512, 4608) pack one
// adjacency row each into the bitmask (forced diagonal). Fusing saves
// a launch and overlaps mask's HBM reads with proj's MFMA work.
// ------------------------------------------------------------------
__global__ __launch_bounds__(256) void gat_prep(
    const float* __restrict__ X, const float* __restrict__ W0,
    const float* __restrict__ Wq, const float* __restrict__ Wk,
    const int* __restrict__ A,
    _Float16* __restrict__ qh, _Float16* __restrict__ ql,
    _Float16* __restrict__ kb, _Float16* __restrict__ vt,
    unsigned short* __restrict__ M16)
{
    __shared__ alignas(16) _Float16 WTh[3][64][72];   // [mat][c_out][c_in], +8 pad
    __shared__ alignas(16) _Float16 WTl[3][64][72];
    const int t = threadIdx.x;
    if (blockIdx.x >= 512) {                          // ---- mask part ----
        const int row = blockIdx.x - 512;
        const int4* ap = (const int4*)(A + (size_t)row * NN + t * 16);
        unsigned m = 0;
        #pragma unroll
        for (int j = 0; j < 4; ++j) {
            int4 a = ap[j];
            m |= (a.x != 0 ? 1u : 0u) << (4*j);
            m |= (a.y != 0 ? 1u : 0u) << (4*j + 1);
            m |= (a.z != 0 ? 1u : 0u) << (4*j + 2);
            m |= (a.w != 0 ? 1u : 0u) << (4*j + 3);
        }
        if (t == (row >> 4)) m |= 1u << (row & 15);
        M16[(size_t)row * 256 + t] = (unsigned short)m;
        return;
    }
    // ---- projection part ----
    const float* Ws[3] = {W0, Wq, Wk};
    for (int e = t; e < 4096; e += 256) {
        int k = e >> 6, c = e & 63;
        #pragma unroll
        for (int m = 0; m < 3; ++m) {
            float w = Ws[m][e];
            _Float16 hi = (_Float16)w;
            WTh[m][c][k] = hi;
            WTl[m][c][k] = (_Float16)(w - (float)hi);
        }
    }
    __syncthreads();
    const int lane = t & 63, wv = t >> 6;
    const int cl = lane & 15, g = lane >> 4;
    {
        int tile = blockIdx.x * 4 + wv;               // 2048 tiles of 16 rows
        int gr = tile * 16;
        const float* xr = X + (size_t)(gr + cl) * CC;
        half8 xh[2], xl[2];
        #pragma unroll
        for (int kf = 0; kf < 2; ++kf) {
            f32x4 a0 = *(const f32x4*)(xr + g*8 + kf*32);
            f32x4 a1 = *(const f32x4*)(xr + g*8 + kf*32 + 4);
            half8 h, l;
            #pragma unroll
            for (int j = 0; j < 4; ++j) {
                _Float16 h0 = (_Float16)a0[j], h1 = (_Float16)a1[j];
                h[j]   = h0; l[j]   = (_Float16)(a0[j] - (float)h0);
                h[j+4] = h1; l[j+4] = (_Float16)(a1[j] - (float)h1);
            }
            xh[kf] = h; xl[kf] = l;
        }
        #pragma unroll
        for (int mat = 1; mat <= 2; ++mat) {
            #pragma unroll
            for (int nt = 0; nt < 4; ++nt) {
                f32x4 acc = {0.f, 0.f, 0.f, 0.f};
                #pragma unroll
                for (int kf = 0; kf < 2; ++kf) {
                    half8 bh = *(const half8*)&WTh[mat][nt*16 + cl][g*8 + kf*32];
                    half8 bl = *(const half8*)&WTl[mat][nt*16 + cl][g*8 + kf*32];
                    acc = __builtin_amdgcn_mfma_f32_16x16x32_f16(xh[kf], bh, acc, 0, 0, 0);
                    acc = __builtin_amdgcn_mfma_f32_16x16x32_f16(xl[kf], bh, acc, 0, 0, 0);
                    acc = __builtin_amdgcn_mfma_f32_16x16x32_f16(xh[kf], bl, acc, 0, 0, 0);
                }
                #pragma unroll
                for (int i = 0; i < 4; ++i) {
                    size_t off = (size_t)(gr + 4*g + i) * CC + nt*16 + cl;
                    if (mat == 1) {
                        float qs = acc[i] * LOG2E;
                        _Float16 hi = (_Float16)qs;
                        qh[off] = hi;
                        ql[off] = (_Float16)(qs - (float)hi);
                    } else {
                        kb[off] = (_Float16)acc[i];
                    }
                }
            }
        }
        {
            int b = gr >> 12, n0 = gr & (NN - 1);
            #pragma unroll
            for (int mt = 0; mt < 4; ++mt) {
                f32x4 acc = {0.f, 0.f, 0.f, 0.f};
                #pragma unroll
                for (int kf = 0; kf < 2; ++kf) {
                    half8 ah = *(const half8*)&WTh[0][mt*16 + cl][g*8 + kf*32];
                    half8 al = *(const half8*)&WTl[0][mt*16 + cl][g*8 + kf*32];
                    acc = __builtin_amdgcn_mfma_f32_16x16x32_f16(ah, xh[kf], acc, 0, 0, 0);
                    acc = __builtin_amdgcn_mfma_f32_16x16x32_f16(al, xh[kf], acc, 0, 0, 0);
                    acc = __builtin_amdgcn_mfma_f32_16x16x32_f16(ah, xl[kf], acc, 0, 0, 0);
                }
                #pragma unroll
                for (int i = 0; i < 4; ++i) {
                    int co = mt*16 + 4*g + i;
                    vt[((size_t)b * CC + co) * NN + n0 + cl] = (_Float16)acc[i];
                }
            }
        }
    }
}

// ------------------------------------------------------------------
// Flash attention, split-K x4, 1024 blocks. Double-buffered K/V LDS
// (36 KB -> 4 blocks/CU) with ONE __syncthreads per chunk. The P
// C-layout -> B-layout transform is done IN-REGISTER via ds_bpermute
// (lanes {cl, cl+16, cl+32, cl+48} exchange pairs), eliminating the
// 18 KB Ps buffer that previously forced single-buffering.
// NO min-waves launch bound (round 5: forcing it spilled 300 MB).
// ------------------------------------------------------------------
__global__ __launch_bounds__(256) void gat_attn(
    const _Float16* __restrict__ qh, const _Float16* __restrict__ ql,
    const _Float16* __restrict__ kf16, const _Float16* __restrict__ vtb,
    const unsigned long long* __restrict__ M,
    _Float16* __restrict__ po, float2* __restrict__ pml)
{
    __shared__ alignas(16) _Float16 Kt[2][64][72];    // [buf][key][c_in]
    __shared__ alignas(16) _Float16 Vt[2][64][72];    // [buf][c_out][key]
    const int t = threadIdx.x;
    const int lane = t & 63, wv = t >> 6;
    const int cl = lane & 15, g = lane >> 4;
    const int blk = blockIdx.x;        // 1024
    const int b  = blk & 7;            // batch == XCD slot
    const int sp = (blk >> 3) & 3;     // key split
    const int qb = blk >> 5;           // q tile 0..31
    const int Q0 = qb * 128 + wv * 32;
    const int c0 = sp * 16;

    half8 qfh[2][2], qfl[2][2];
    #pragma unroll
    for (int qt = 0; qt < 2; ++qt) {
        const _Float16* qrh = qh + ((size_t)b * NN + Q0 + qt*16 + cl) * CC;
        const _Float16* qrl = ql + ((size_t)b * NN + Q0 + qt*16 + cl) * CC;
        qfh[qt][0] = *(const half8*)(qrh + g*8);
        qfh[qt][1] = *(const half8*)(qrh + g*8 + 32);
        qfl[qt][0] = *(const half8*)(qrl + g*8);
        qfl[qt][1] = *(const half8*)(qrl + g*8 + 32);
    }
    const _Float16* kg = kf16 + (size_t)b * NN * CC;
    const _Float16* vg = vtb + (size_t)b * CC * NN;

    // bpermute byte-addresses of the two source lanes this lane pulls from
    const int addrA = 4 * (cl + 32 * (g & 1));      // h = 0
    const int addrB = addrA + 64;                   // h = 1

    f32x4 o[2][4] = {};
    float m_run[2] = {MASKV, MASKV}, l_run[2] = {0.f, 0.f};

    uint4 pk0, pk1, pv0, pv1;
    unsigned long long pmA, pmB;
    auto loadchunk = [&](int kc) {
        const uint4* ks = (const uint4*)(kg + (size_t)kc * 64 * CC);
        pk0 = ks[t];
        pk1 = ks[t + 256];
        const _Float16* vs = vg + kc * 64;
        pv0 = *(const uint4*)(vs + (size_t)(t >> 3) * NN + (t & 7) * 8);
        pv1 = *(const uint4*)(vs + (size_t)((t >> 3) + 32) * NN + (t & 7) * 8);
        pmA = M[(size_t)(Q0 + cl) * 64 + kc];
        pmB = M[(size_t)(Q0 + 16 + cl) * 64 + kc];
    };
    auto storebuf = [&](int bu) {
        *(uint4*)&Kt[bu][t >> 3][(t & 7) * 8] = pk0;
        *(uint4*)&Kt[bu][(t >> 3) + 32][(t & 7) * 8] = pk1;
        *(uint4*)&Vt[bu][t >> 3][(t & 7) * 8] = pv0;
        *(uint4*)&Vt[bu][(t >> 3) + 32][(t & 7) * 8] = pv1;
    };

    loadchunk(c0);
    storebuf(0);
    unsigned long long cmA = pmA, cmB = pmB;
    loadchunk(c0 + 1);
    unsigned long long nmA = pmA, nmB = pmB;
    __syncthreads();

    for (int kc = 0; kc < 16; ++kc) {
        const int cur = kc & 1;

        // S^T tiles from current buffer
        f32x4 sc[2][4] = {};
        #pragma unroll
        for (int kt = 0; kt < 4; ++kt) {
            #pragma unroll
            for (int kf = 0; kf < 2; ++kf) {
                half8 ka = *(const half8*)&Kt[cur][kt*16 + cl][g*8 + kf*32];
                sc[0][kt] = __builtin_amdgcn_mfma_f32_16x16x32_f16(ka, qfh[0][kf], sc[0][kt], 0, 0, 0);
                sc[0][kt] = __builtin_amdgcn_mfma_f32_16x16x32_f16(ka, qfl[0][kf], sc[0][kt], 0, 0, 0);
                sc[1][kt] = __builtin_amdgcn_mfma_f32_16x16x32_f16(ka, qfh[1][kf], sc[1][kt], 0, 0, 0);
                sc[1][kt] = __builtin_amdgcn_mfma_f32_16x16x32_f16(ka, qfl[1][kf], sc[1][kt], 0, 0, 0);
            }
        }

        // stage next chunk into the other buffer; start load of chunk+2
        if (kc < 15) storebuf(cur ^ 1);
        if (kc < 14) loadchunk(c0 + kc + 2);

        // softmax (exp2 domain, fp32 — numerics identical to round 6)
        half8 pfq[2][2];
        #pragma unroll
        for (int qt = 0; qt < 2; ++qt) {
            const unsigned long long cm = qt ? cmB : cmA;
            const unsigned mwx = (unsigned)cm, mwy = (unsigned)(cm >> 32);
            float sv[16];
            float mx = MASKV;
            #pragma unroll
            for (int kt = 0; kt < 4; ++kt) {
                unsigned wmw = (kt < 2) ? mwx : mwy;
                #pragma unroll
                for (int i = 0; i < 4; ++i) {
                    float x = sc[qt][kt][i];
                    x = fmaxf(x, 0.01f * x);              // leaky_relu
                    int bit = ((kt & 1) * 16) + 4*g + i;
                    x = ((wmw >> bit) & 1u) ? x : MASKV;
                    sv[kt*4 + i] = x;
                    mx = fmaxf(mx, x);
                }
            }
            mx = fmaxf(mx, __shfl_xor(mx, 16));
            mx = fmaxf(mx, __shfl_xor(mx, 32));
            if (__any(mx > m_run[qt])) {                   // wave-uniform skip
                float nm = fmaxf(m_run[qt], mx);
                float alpha = __builtin_amdgcn_exp2f(m_run[qt] - nm);
                m_run[qt] = nm;
                l_run[qt] *= alpha;
                #pragma unroll
                for (int ct = 0; ct < 4; ++ct) o[qt][ct] *= alpha;
            }
            float lsum = 0.f;
            float p[16];
            #pragma unroll
            for (int j = 0; j < 16; ++j) {
                p[j] = __builtin_amdgcn_exp2f(sv[j] - m_run[qt]);  // masked -> 0
                lsum += p[j];
            }
            l_run[qt] += lsum;
            // pack to fp16 pairs (C-layout): pair P = kt*2 + (i>>1)
            unsigned p2[8];
            #pragma unroll
            for (int kt = 0; kt < 4; ++kt) {
                union { fp16x2 h; unsigned u; } c0u, c1u;
                c0u.h = __builtin_amdgcn_cvt_pkrtz(p[kt*4+0], p[kt*4+1]);
                c1u.h = __builtin_amdgcn_cvt_pkrtz(p[kt*4+2], p[kt*4+3]);
                p2[kt*2]     = c0u.u;
                p2[kt*2 + 1] = c1u.u;
            }
            // C->B layout transform in-register: lane (cl,g) pulls
            // pair [4f + 2*(g>>1) + (m&1)] from lane cl+16*(2*(g&1)+(m>>1)).
            const bool ghi = (g & 2) != 0;
            #pragma unroll
            for (int f = 0; f < 2; ++f) {
                unsigned RA[4], RB[4];
                #pragma unroll
                for (int P = 0; P < 4; ++P) {
                    RA[P] = (unsigned)__builtin_amdgcn_ds_bpermute(addrA, (int)p2[4*f + P]);
                    RB[P] = (unsigned)__builtin_amdgcn_ds_bpermute(addrB, (int)p2[4*f + P]);
                }
                union { unsigned u[4]; half8 h; } bf;
                bf.u[0] = ghi ? RA[2] : RA[0];   // m=0: pair (m&1)=0, h=0
                bf.u[1] = ghi ? RA[3] : RA[1];   // m=1: pair 1, h=0
                bf.u[2] = ghi ? RB[2] : RB[0];   // m=2: pair 0, h=1
                bf.u[3] = ghi ? RB[3] : RB[1];   // m=3: pair 1, h=1
                pfq[qt][f] = bf.h;
            }
        }

        // O^T += V^T * P^T
        #pragma unroll
        for (int ct = 0; ct < 4; ++ct) {
            half8 vf0 = *(const half8*)&Vt[cur][ct*16 + cl][g*8];
            half8 vf1 = *(const half8*)&Vt[cur][ct*16 + cl][g*8 + 32];
            #pragma unroll
            for (int qt = 0; qt < 2; ++qt) {
                o[qt][ct] = __builtin_amdgcn_mfma_f32_16x16x32_f16(vf0, pfq[qt][0], o[qt][ct], 0, 0, 0);
                o[qt][ct] = __builtin_amdgcn_mfma_f32_16x16x32_f16(vf1, pfq[qt][1], o[qt][ct], 0, 0, 0);
            }
        }
        cmA = nmA; cmB = nmB;
        nmA = pmA; nmB = pmB;
        __syncthreads();                 // protects buf `cur` before next write
    }

    // epilogue: store UNNORMALIZED fp16 partial o + (m, l) for combine
    #pragma unroll
    for (int qt = 0; qt < 2; ++qt) {
        float lt = l_run[qt];
        lt += __shfl_xor(lt, 16);
        lt += __shfl_xor(lt, 32);
        size_t base = (size_t)sp * (BATCH * NN) + (size_t)b * NN + Q0 + qt*16 + cl;
        _Float16* orow = po + base * 64;
        #pragma unroll
        for (int ct = 0; ct < 4; ++ct) {
            union { fp16x2 h; unsigned u; } o0u, o1u;
            o0u.h = __builtin_amdgcn_cvt_pkrtz(o[qt][ct][0], o[qt][ct][1]);
            o1u.h = __builtin_amdgcn_cvt_pkrtz(o[qt][ct][2], o[qt][ct][3]);
            uint2 ow = {o0u.u, o1u.u};
            *(uint2*)(orow + ct*16 + 4*g) = ow;
        }
        if (g == 0) pml[base] = make_float2(m_run[qt], lt);
    }
}

// ------------------------------------------------------------------
// Combine the 4 split-K partials: out = sum_s w_s*o_s / sum_s w_s*l_s.
// ------------------------------------------------------------------
__global__ __launch_bounds__(256) void gat_comb(
    const _Float16* __restrict__ po, const float2* __restrict__ pml,
    float* __restrict__ out)
{
    int gid = blockIdx.x * 256 + threadIdx.x;     // 131072 threads
    int row = gid >> 2;
    int col = (gid & 3) * 16;
    float2 ml[4];
    float Mx = MASKV;
    #pragma unroll
    for (int s = 0; s < 4; ++s) {
        ml[s] = pml[s * (BATCH * NN) + row];
        Mx = fmaxf(Mx, ml[s].x);
    }
    float w[4], den = 0.f;
    #pragma unroll
    for (int s = 0; s < 4; ++s) {
        w[s] = __builtin_amdgcn_exp2f(ml[s].x - Mx);
        den += w[s] * ml[s].y;
    }
    float inv = 1.0f / den;
    float acc[16] = {};
    #pragma unroll
    for (int s = 0; s < 4; ++s) {
        const _Float16* p = po + ((size_t)s * (BATCH * NN) + row) * 64 + col;
        float a = w[s] * inv;
        half8 v0 = *(const half8*)(p);
        half8 v1 = *(const half8*)(p + 8);
        #pragma unroll
        for (int j = 0; j < 8; ++j) {
            acc[j]     += a * (float)v0[j];
            acc[j + 8] += a * (float)v1[j];
        }
    }
    float* op = out + (size_t)row * 64 + col;
    #pragma unroll
    for (int i = 0; i < 4; ++i) {
        f32x4 r = {acc[4*i], acc[4*i+1], acc[4*i+2], acc[4*i+3]};
        *(f32x4*)(op + i*4) = r;
    }
}

extern "C" void kernel_launch(void* const* d_in, const int* in_sizes, int n_in,
                              void* d_out, int out_size, void* d_ws, size_t ws_size,
                              hipStream_t stream) {
    const float* X  = (const float*)d_in[0];
    const int*   A  = (const int*)d_in[1];
    const float* W0 = (const float*)d_in[2];
    const float* Wq = (const float*)d_in[3];
    const float* Wk = (const float*)d_in[4];
    float* out = (float*)d_out;
    char* ws = (char*)d_ws;
    const size_t SZ = (size_t)BATCH * NN * CC * 2;        // 4 MB per fp16 tensor
    _Float16* qh  = (_Float16*)(ws);
    _Float16* ql  = (_Float16*)(ws + SZ);
    _Float16* kbf = (_Float16*)(ws + 2*SZ);
    _Float16* vtb = (_Float16*)(ws + 3*SZ);
    char* Mbase = ws + 4*SZ;                               // 2 MB mask
    _Float16* po = (_Float16*)(Mbase + 2*1024*1024);       // 16 MB (4 splits fp16)
    float2* pml  = (float2*)(Mbase + 2*1024*1024 + 4*SZ);  // 1 MB

    hipLaunchKernelGGL(gat_prep, dim3(4608), dim3(256), 0, stream,
                       X, W0, Wq, Wk, A, qh, ql, kbf, vtb, (unsigned short*)Mbase);
    hipLaunchKernelGGL(gat_attn, dim3(1024), dim3(256), 0, stream, qh, ql, kbf, vtb,
                       (const unsigned long long*)Mbase, po, pml);
    hipLaunchKernelGGL(gat_comb, dim3(512),  dim3(256), 0, stream, po, pml, out);
}

// Round 10
// 207.998 us; speedup vs baseline: 1.0291x; 1.0291x over previous
//
#include <hip/hip_runtime.h>
#include <stdint.h>

#define BATCH 8
#define NN 4096
#define CC 64
#define MASKV -1.0e30f
#define LOG2E 1.4426950408889634f

typedef _Float16 half8 __attribute__((ext_vector_type(8)));
typedef __fp16 fp16x2 __attribute__((ext_vector_type(2)));
typedef float f32x4 __attribute__((ext_vector_type(4)));

// ------------------------------------------------------------------
// Fused prep: blocks [0,512) projections (q fp16 pre-scaled by log2e,
// k fp16, vT fp16 [b][c][n]); blocks [512,4608) pack one adjacency
// row into the bitmask (forced diagonal). Projection compute is
// split-compensated (hi/lo x, hi/lo W); only fp16 STORAGE rounding
// survives into the attention matmuls.
// ------------------------------------------------------------------
__global__ __launch_bounds__(256) void gat_prep(
    const float* __restrict__ X, const float* __restrict__ W0,
    const float* __restrict__ Wq, const float* __restrict__ Wk,
    const int* __restrict__ A,
    _Float16* __restrict__ qh,
    _Float16* __restrict__ kb, _Float16* __restrict__ vt,
    unsigned short* __restrict__ M16)
{
    __shared__ alignas(16) _Float16 WTh[3][64][72];   // [mat][c_out][c_in], +8 pad
    __shared__ alignas(16) _Float16 WTl[3][64][72];
    const int t = threadIdx.x;
    if (blockIdx.x >= 512) {                          // ---- mask part ----
        const int row = blockIdx.x - 512;
        const int4* ap = (const int4*)(A + (size_t)row * NN + t * 16);
        unsigned m = 0;
        #pragma unroll
        for (int j = 0; j < 4; ++j) {
            int4 a = ap[j];
            m |= (a.x != 0 ? 1u : 0u) << (4*j);
            m |= (a.y != 0 ? 1u : 0u) << (4*j + 1);
            m |= (a.z != 0 ? 1u : 0u) << (4*j + 2);
            m |= (a.w != 0 ? 1u : 0u) << (4*j + 3);
        }
        if (t == (row >> 4)) m |= 1u << (row & 15);
        M16[(size_t)row * 256 + t] = (unsigned short)m;
        return;
    }
    // ---- projection part ----
    const float* Ws[3] = {W0, Wq, Wk};
    for (int e = t; e < 4096; e += 256) {
        int k = e >> 6, c = e & 63;
        #pragma unroll
        for (int m = 0; m < 3; ++m) {
            float w = Ws[m][e];
            _Float16 hi = (_Float16)w;
            WTh[m][c][k] = hi;
            WTl[m][c][k] = (_Float16)(w - (float)hi);
        }
    }
    __syncthreads();
    const int lane = t & 63, wv = t >> 6;
    const int cl = lane & 15, g = lane >> 4;
    {
        int tile = blockIdx.x * 4 + wv;               // 2048 tiles of 16 rows
        int gr = tile * 16;
        const float* xr = X + (size_t)(gr + cl) * CC;
        half8 xh[2], xl[2];
        #pragma unroll
        for (int kf = 0; kf < 2; ++kf) {
            f32x4 a0 = *(const f32x4*)(xr + g*8 + kf*32);
            f32x4 a1 = *(const f32x4*)(xr + g*8 + kf*32 + 4);
            half8 h, l;
            #pragma unroll
            for (int j = 0; j < 4; ++j) {
                _Float16 h0 = (_Float16)a0[j], h1 = (_Float16)a1[j];
                h[j]   = h0; l[j]   = (_Float16)(a0[j] - (float)h0);
                h[j+4] = h1; l[j+4] = (_Float16)(a1[j] - (float)h1);
            }
            xh[kf] = h; xl[kf] = l;
        }
        #pragma unroll
        for (int mat = 1; mat <= 2; ++mat) {
            #pragma unroll
            for (int nt = 0; nt < 4; ++nt) {
                f32x4 acc = {0.f, 0.f, 0.f, 0.f};
                #pragma unroll
                for (int kf = 0; kf < 2; ++kf) {
                    half8 bh = *(const half8*)&WTh[mat][nt*16 + cl][g*8 + kf*32];
                    half8 bl = *(const half8*)&WTl[mat][nt*16 + cl][g*8 + kf*32];
                    acc = __builtin_amdgcn_mfma_f32_16x16x32_f16(xh[kf], bh, acc, 0, 0, 0);
                    acc = __builtin_amdgcn_mfma_f32_16x16x32_f16(xl[kf], bh, acc, 0, 0, 0);
                    acc = __builtin_amdgcn_mfma_f32_16x16x32_f16(xh[kf], bl, acc, 0, 0, 0);
                }
                #pragma unroll
                for (int i = 0; i < 4; ++i) {
                    size_t off = (size_t)(gr + 4*g + i) * CC + nt*16 + cl;
                    if (mat == 1) qh[off] = (_Float16)(acc[i] * LOG2E);
                    else          kb[off] = (_Float16)acc[i];
                }
            }
        }
        {
            int b = gr >> 12, n0 = gr & (NN - 1);
            #pragma unroll
            for (int mt = 0; mt < 4; ++mt) {
                f32x4 acc = {0.f, 0.f, 0.f, 0.f};
                #pragma unroll
                for (int kf = 0; kf < 2; ++kf) {
                    half8 ah = *(const half8*)&WTh[0][mt*16 + cl][g*8 + kf*32];
                    half8 al = *(const half8*)&WTl[0][mt*16 + cl][g*8 + kf*32];
                    acc = __builtin_amdgcn_mfma_f32_16x16x32_f16(ah, xh[kf], acc, 0, 0, 0);
                    acc = __builtin_amdgcn_mfma_f32_16x16x32_f16(al, xh[kf], acc, 0, 0, 0);
                    acc = __builtin_amdgcn_mfma_f32_16x16x32_f16(ah, xl[kf], acc, 0, 0, 0);
                }
                #pragma unroll
                for (int i = 0; i < 4; ++i) {
                    int co = mt*16 + 4*g + i;
                    vt[((size_t)b * CC + co) * NN + n0 + cl] = (_Float16)acc[i];
                }
            }
        }
    }
}

// ------------------------------------------------------------------
// Flash attention, split-K x4, 1024 blocks. EXACT R7-verified body
// (staging, dbuf stride-72, 1 barrier/chunk, pre-exp MASKV masking
// with MASKED running max — the fp16 P/o scaling guarantee — and the
// bpermute C->B transform) with ONE change: q stored/used as single
// fp16 (drops qfl frags + 16 MFMAs/chunk). R9's unmasked-max post-exp
// masking broke fp16 scaling (gap-underflow) — do not reintroduce.
// ------------------------------------------------------------------
__global__ __launch_bounds__(256) void gat_attn(
    const _Float16* __restrict__ qh,
    const _Float16* __restrict__ kf16, const _Float16* __restrict__ vtb,
    const unsigned long long* __restrict__ M,
    _Float16* __restrict__ po, float2* __restrict__ pml)
{
    __shared__ alignas(16) _Float16 Kt[2][64][72];    // [buf][key][c_in]
    __shared__ alignas(16) _Float16 Vt[2][64][72];    // [buf][c_out][key]
    const int t = threadIdx.x;
    const int lane = t & 63, wv = t >> 6;
    const int cl = lane & 15, g = lane >> 4;
    const int blk = blockIdx.x;        // 1024
    const int b  = blk & 7;            // batch == XCD slot
    const int sp = (blk >> 3) & 3;     // key split
    const int qb = blk >> 5;           // q tile 0..31
    const int Q0 = qb * 128 + wv * 32;
    const int c0 = sp * 16;

    half8 qf[2][2];
    #pragma unroll
    for (int qt = 0; qt < 2; ++qt) {
        const _Float16* qr = qh + ((size_t)b * NN + Q0 + qt*16 + cl) * CC;
        qf[qt][0] = *(const half8*)(qr + g*8);
        qf[qt][1] = *(const half8*)(qr + g*8 + 32);
    }
    const _Float16* kg = kf16 + (size_t)b * NN * CC;
    const _Float16* vg = vtb + (size_t)b * CC * NN;

    // bpermute source-lane byte addresses for the P C->B transform
    const int addrA = 4 * (cl + 32 * (g & 1));
    const int addrB = addrA + 64;
    const bool ghi = (g & 2) != 0;

    f32x4 o[2][4] = {};
    float m_run[2] = {MASKV, MASKV}, l_run[2] = {0.f, 0.f};

    uint4 pk0, pk1, pv0, pv1;
    unsigned long long pmA, pmB;
    auto loadchunk = [&](int kc) {
        const uint4* ks = (const uint4*)(kg + (size_t)kc * 64 * CC);
        pk0 = ks[t];
        pk1 = ks[t + 256];
        const _Float16* vs = vg + kc * 64;
        pv0 = *(const uint4*)(vs + (size_t)(t >> 3) * NN + (t & 7) * 8);
        pv1 = *(const uint4*)(vs + (size_t)((t >> 3) + 32) * NN + (t & 7) * 8);
        pmA = M[(size_t)(Q0 + cl) * 64 + kc];
        pmB = M[(size_t)(Q0 + 16 + cl) * 64 + kc];
    };
    auto storebuf = [&](int bu) {
        *(uint4*)&Kt[bu][t >> 3][(t & 7) * 8] = pk0;
        *(uint4*)&Kt[bu][(t >> 3) + 32][(t & 7) * 8] = pk1;
        *(uint4*)&Vt[bu][t >> 3][(t & 7) * 8] = pv0;
        *(uint4*)&Vt[bu][(t >> 3) + 32][(t & 7) * 8] = pv1;
    };

    loadchunk(c0);
    storebuf(0);
    unsigned long long cmA = pmA, cmB = pmB;
    loadchunk(c0 + 1);
    unsigned long long nmA = pmA, nmB = pmB;
    __syncthreads();

    for (int kc = 0; kc < 16; ++kc) {
        const int cur = kc & 1;

        // S^T tiles: D[key][qrow], single-fp16 q
        f32x4 sc[2][4] = {};
        #pragma unroll
        for (int kt = 0; kt < 4; ++kt) {
            #pragma unroll
            for (int kf = 0; kf < 2; ++kf) {
                half8 ka = *(const half8*)&Kt[cur][kt*16 + cl][g*8 + kf*32];
                sc[0][kt] = __builtin_amdgcn_mfma_f32_16x16x32_f16(ka, qf[0][kf], sc[0][kt], 0, 0, 0);
                sc[1][kt] = __builtin_amdgcn_mfma_f32_16x16x32_f16(ka, qf[1][kf], sc[1][kt], 0, 0, 0);
            }
        }

        // stage next chunk into the other buffer; start load of chunk+2
        if (kc < 15) storebuf(cur ^ 1);
        if (kc < 14) loadchunk(c0 + kc + 2);

        // softmax (exp2 domain) — R7-verified: mask BEFORE max (MASKV),
        // masked running max keeps P/o fp16 well-scaled.
        half8 pfq[2][2];
        #pragma unroll
        for (int qt = 0; qt < 2; ++qt) {
            const unsigned long long cm = qt ? cmB : cmA;
            const unsigned mwx = (unsigned)cm, mwy = (unsigned)(cm >> 32);
            float sv[16];
            float mx = MASKV;
            #pragma unroll
            for (int kt = 0; kt < 4; ++kt) {
                unsigned wmw = (kt < 2) ? mwx : mwy;
                #pragma unroll
                for (int i = 0; i < 4; ++i) {
                    float x = sc[qt][kt][i];
                    x = fmaxf(x, 0.01f * x);              // leaky_relu
                    int bit = ((kt & 1) * 16) + 4*g + i;
                    x = ((wmw >> bit) & 1u) ? x : MASKV;
                    sv[kt*4 + i] = x;
                    mx = fmaxf(mx, x);
                }
            }
            mx = fmaxf(mx, __shfl_xor(mx, 16));
            mx = fmaxf(mx, __shfl_xor(mx, 32));
            if (__any(mx > m_run[qt])) {                   // wave-uniform skip
                float nm = fmaxf(m_run[qt], mx);
                float alpha = __builtin_amdgcn_exp2f(m_run[qt] - nm);
                m_run[qt] = nm;
                l_run[qt] *= alpha;
                #pragma unroll
                for (int ct = 0; ct < 4; ++ct) o[qt][ct] *= alpha;
            }
            float lsum = 0.f;
            float p[16];
            #pragma unroll
            for (int j = 0; j < 16; ++j) {
                p[j] = __builtin_amdgcn_exp2f(sv[j] - m_run[qt]);  // masked -> 0
                lsum += p[j];
            }
            l_run[qt] += lsum;
            unsigned p2[8];
            #pragma unroll
            for (int kt = 0; kt < 4; ++kt) {
                union { fp16x2 h; unsigned u32; } c0u, c1u;
                c0u.h = __builtin_amdgcn_cvt_pkrtz(p[kt*4+0], p[kt*4+1]);
                c1u.h = __builtin_amdgcn_cvt_pkrtz(p[kt*4+2], p[kt*4+3]);
                p2[kt*2]     = c0u.u32;
                p2[kt*2 + 1] = c1u.u32;
            }
            // C->B transform in-register (verified R7)
            #pragma unroll
            for (int f = 0; f < 2; ++f) {
                unsigned RA[4], RB[4];
                #pragma unroll
                for (int P = 0; P < 4; ++P) {
                    RA[P] = (unsigned)__builtin_amdgcn_ds_bpermute(addrA, (int)p2[4*f + P]);
                    RB[P] = (unsigned)__builtin_amdgcn_ds_bpermute(addrB, (int)p2[4*f + P]);
                }
                union { unsigned u32[4]; half8 h; } bf;
                bf.u32[0] = ghi ? RA[2] : RA[0];
                bf.u32[1] = ghi ? RA[3] : RA[1];
                bf.u32[2] = ghi ? RB[2] : RB[0];
                bf.u32[3] = ghi ? RB[3] : RB[1];
                pfq[qt][f] = bf.h;
            }
        }

        // O^T += V^T * P^T
        #pragma unroll
        for (int ct = 0; ct < 4; ++ct) {
            #pragma unroll
            for (int kf = 0; kf < 2; ++kf) {
                half8 vf = *(const half8*)&Vt[cur][ct*16 + cl][g*8 + kf*32];
                o[0][ct] = __builtin_amdgcn_mfma_f32_16x16x32_f16(vf, pfq[0][kf], o[0][ct], 0, 0, 0);
                o[1][ct] = __builtin_amdgcn_mfma_f32_16x16x32_f16(vf, pfq[1][kf], o[1][ct], 0, 0, 0);
            }
        }
        cmA = nmA; cmB = nmB;
        nmA = pmA; nmB = pmB;
        __syncthreads();                 // protects buf `cur` before next write
    }

    // epilogue: store UNNORMALIZED fp16 partial o + (m, l) for combine
    #pragma unroll
    for (int qt = 0; qt < 2; ++qt) {
        float lt = l_run[qt];
        lt += __shfl_xor(lt, 16);
        lt += __shfl_xor(lt, 32);
        size_t base = (size_t)sp * (BATCH * NN) + (size_t)b * NN + Q0 + qt*16 + cl;
        _Float16* orow = po + base * 64;
        #pragma unroll
        for (int ct = 0; ct < 4; ++ct) {
            union { fp16x2 h; unsigned u32; } o0u, o1u;
            o0u.h = __builtin_amdgcn_cvt_pkrtz(o[qt][ct][0], o[qt][ct][1]);
            o1u.h = __builtin_amdgcn_cvt_pkrtz(o[qt][ct][2], o[qt][ct][3]);
            uint2 ow = {o0u.u32, o1u.u32};
            *(uint2*)(orow + ct*16 + 4*g) = ow;
        }
        if (g == 0) pml[base] = make_float2(m_run[qt], lt);
    }
}

// ------------------------------------------------------------------
// Combine the 4 split-K partials: out = sum_s w_s*o_s / sum_s w_s*l_s.
// ------------------------------------------------------------------
__global__ __launch_bounds__(256) void gat_comb(
    const _Float16* __restrict__ po, const float2* __restrict__ pml,
    float* __restrict__ out)
{
    int gid = blockIdx.x * 256 + threadIdx.x;     // 131072 threads
    int row = gid >> 2;
    int col = (gid & 3) * 16;
    float2 ml[4];
    float Mx = MASKV;
    #pragma unroll
    for (int s = 0; s < 4; ++s) {
        ml[s] = pml[s * (BATCH * NN) + row];
        Mx = fmaxf(Mx, ml[s].x);
    }
    float w[4], den = 0.f;
    #pragma unroll
    for (int s = 0; s < 4; ++s) {
        w[s] = __builtin_amdgcn_exp2f(ml[s].x - Mx);
        den += w[s] * ml[s].y;
    }
    float inv = 1.0f / fmaxf(den, 1e-30f);        // diag => den>0; clamp = NaN guard
    float acc[16] = {};
    #pragma unroll
    for (int s = 0; s < 4; ++s) {
        const _Float16* p = po + ((size_t)s * (BATCH * NN) + row) * 64 + col;
        float a = w[s] * inv;
        half8 v0 = *(const half8*)(p);
        half8 v1 = *(const half8*)(p + 8);
        #pragma unroll
        for (int j = 0; j < 8; ++j) {
            acc[j]     += a * (float)v0[j];
            acc[j + 8] += a * (float)v1[j];
        }
    }
    float* op = out + (size_t)row * 64 + col;
    #pragma unroll
    for (int i = 0; i < 4; ++i) {
        f32x4 r = {acc[4*i], acc[4*i+1], acc[4*i+2], acc[4*i+3]};
        *(f32x4*)(op + i*4) = r;
    }
}

extern "C" void kernel_launch(void* const* d_in, const int* in_sizes, int n_in,
                              void* d_out, int out_size, void* d_ws, size_t ws_size,
                              hipStream_t stream) {
    const float* X  = (const float*)d_in[0];
    const int*   A  = (const int*)d_in[1];
    const float* W0 = (const float*)d_in[2];
    const float* Wq = (const float*)d_in[3];
    const float* Wk = (const float*)d_in[4];
    float* out = (float*)d_out;
    char* ws = (char*)d_ws;
    const size_t SZ = (size_t)BATCH * NN * CC * 2;        // 4 MB per fp16 tensor
    _Float16* qh  = (_Float16*)(ws);
    _Float16* kbf = (_Float16*)(ws + SZ);
    _Float16* vtb = (_Float16*)(ws + 2*SZ);
    char* Mbase = ws + 3*SZ;                               // 2 MB mask
    _Float16* po = (_Float16*)(Mbase + 2*1024*1024);       // 16 MB (4 splits fp16)
    float2* pml  = (float2*)(Mbase + 2*1024*1024 + 4*SZ);  // 1 MB

    hipLaunchKernelGGL(gat_prep, dim3(4608), dim3(256), 0, stream,
                       X, W0, Wq, Wk, A, qh, kbf, vtb, (unsigned short*)Mbase);
    hipLaunchKernelGGL(gat_attn, dim3(1024), dim3(256), 0, stream, qh, kbf, vtb,
                       (const unsigned long long*)Mbase, po, pml);
    hipLaunchKernelGGL(gat_comb, dim3(512),  dim3(256), 0, stream, po, pml, out);
}